// Round 18
// baseline (754.906 us; speedup 1.0000x reference)
//
#include <hip/hip_runtime.h>
#include <math.h>

#define NP 8192
#define NF 16384
#define G  16                 // grid cells per dim
#define NC (G*G*G)            // 4096 cells
#define H  (1.0/16.0)

// ---------------------------------------------------------------------------
// K_init: zero cell histogram + Adagrad clr table (re-run every call: the
// harness does not re-poison, we must re-init our own state).
// ---------------------------------------------------------------------------
__global__ __launch_bounds__(256) void k_init(int* __restrict__ cnt,
                                              double* __restrict__ clrtab) {
    int t = blockIdx.x * 256 + threadIdx.x;
    if (t < NC) cnt[t] = 0;
    if (blockIdx.x == 0 && threadIdx.x < 50)
        clrtab[threadIdx.x] = 0.2 / (1.0 + (double)threadIdx.x * 0.1);
}

// ---------------------------------------------------------------------------
// K0: face centers in f64 + |c|^2 (np: c=(v0+v1+v2)/3), cell id, histogram.
// ---------------------------------------------------------------------------
__global__ __launch_bounds__(256) void k_centers(const float* __restrict__ mV,
                                                 const int* __restrict__ mF,
                                                 double* __restrict__ ctr,
                                                 int* __restrict__ cellof,
                                                 int* __restrict__ cnt) {
    int f = blockIdx.x * 256 + threadIdx.x;
    if (f >= NF) return;
    int i0 = mF[3*f+0], i1 = mF[3*f+1], i2 = mF[3*f+2];
    double cx = ((double)mV[3*i0+0] + (double)mV[3*i1+0] + (double)mV[3*i2+0]) / 3.0;
    double cy = ((double)mV[3*i0+1] + (double)mV[3*i1+1] + (double)mV[3*i2+1]) / 3.0;
    double cz = ((double)mV[3*i0+2] + (double)mV[3*i1+2] + (double)mV[3*i2+2]) / 3.0;
    ctr[4*f+0] = cx; ctr[4*f+1] = cy; ctr[4*f+2] = cz;
    ctr[4*f+3] = cx*cx + cy*cy + cz*cz;
    int ix = min(G-1, max(0, (int)(cx * (double)G)));
    int iy = min(G-1, max(0, (int)(cy * (double)G)));
    int iz = min(G-1, max(0, (int)(cz * (double)G)));
    int cell = (iz * G + iy) * G + ix;
    cellof[f] = cell;
    atomicAdd(&cnt[cell], 1);
}

// ---------------------------------------------------------------------------
// K_prefix: exclusive prefix sum of the 4096-cell histogram (1 block).
// off[NC] = NF sentinel. cursor = copy of off for the scatter pass.
// ---------------------------------------------------------------------------
__global__ __launch_bounds__(256) void k_prefix(const int* __restrict__ cnt,
                                                int* __restrict__ off,
                                                int* __restrict__ cursor) {
    __shared__ int part[256];
    int t = threadIdx.x;
    int base = t * 16;
    int loc[16];
    int s = 0;
    #pragma unroll
    for (int i = 0; i < 16; ++i) { loc[i] = s; s += cnt[base + i]; }
    part[t] = s;
    __syncthreads();
    if (t == 0) {
        int run = 0;
        for (int i = 0; i < 256; ++i) { int v = part[i]; part[i] = run; run += v; }
    }
    __syncthreads();
    int pb = part[t];
    #pragma unroll
    for (int i = 0; i < 16; ++i) {
        off[base + i]    = pb + loc[i];
        cursor[base + i] = pb + loc[i];
    }
    if (t == 255) off[NC] = pb + s;   // == NF
}

// ---------------------------------------------------------------------------
// K_scatter: counting-sort faces into cell-contiguous slist. Order within a
// cell is atomic-nondeterministic; downstream lex (key,idx) min is
// order-independent -> outputs deterministic.
// ---------------------------------------------------------------------------
__global__ __launch_bounds__(256) void k_scatter(const int* __restrict__ cellof,
                                                 int* __restrict__ cursor,
                                                 int* __restrict__ slist) {
    int f = blockIdx.x * 256 + threadIdx.x;
    if (f >= NF) return;
    int c = cellof[f];
    int pos = atomicAdd(&cursor[c], 1);
    slist[pos] = f;
}

// ---------------------------------------------------------------------------
// K1: grid 1-NN, one thread per point. Expanding Chebyshev rings; key =
// cc - 2 q.c in f64 (same expression as the proven full scan); lex (key,idx)
// min. Termination: before ring r, if ((r-1)h)^2 - 1e-9 > bestKey + qq, all
// unscanned faces are STRICTLY worse (conservative bound; eps absorbs the
// association ulp between key+qq and np's d2) -> no tie can be missed ->
// winner identical to the full-scan argmin with first-index tie-break.
// Winner's d2 recomputed with np's exact association for the outlier test.
// ---------------------------------------------------------------------------
__global__ __launch_bounds__(256) void k_knn_grid(const float* __restrict__ qV,
                                                  const double* __restrict__ ctr,
                                                  const int* __restrict__ off,
                                                  const int* __restrict__ slist,
                                                  float* __restrict__ out,
                                                  int* __restrict__ fidx_ws,
                                                  int* __restrict__ valid_ws) {
    int p = blockIdx.x * 256 + threadIdx.x;
    if (p >= NP) return;
    double qx = (double)qV[3*p+0], qy = (double)qV[3*p+1], qz = (double)qV[3*p+2];
    double qq = qx*qx + qy*qy + qz*qz;
    int icx = min(G-1, max(0, (int)(qx * (double)G)));
    int icy = min(G-1, max(0, (int)(qy * (double)G)));
    int icz = min(G-1, max(0, (int)(qz * (double)G)));

    double bestKey = 1e300; int bi = 0x7fffffff;
    const double4* ctr4 = (const double4*)ctr;

    for (int r = 0; r < G; ++r) {
        if (r > 0 && bi != 0x7fffffff) {
            double dmin = (double)(r - 1) * H;
            if (dmin*dmin - 1e-9 > bestKey + qq) break;   // strictly worse beyond
        }
        int x0 = max(0, icx - r), x1 = min(G-1, icx + r);
        int y0 = max(0, icy - r), y1 = min(G-1, icy + r);
        int z0 = max(0, icz - r), z1 = min(G-1, icz + r);
        for (int z = z0; z <= z1; ++z) {
            int dz = z - icz; dz = dz < 0 ? -dz : dz;
            for (int y = y0; y <= y1; ++y) {
                int dy = y - icy; dy = dy < 0 ? -dy : dy;
                for (int x = x0; x <= x1; ++x) {
                    int dx = x - icx; dx = dx < 0 ? -dx : dx;
                    int cheb = dx > dy ? dx : dy;
                    cheb = cheb > dz ? cheb : dz;
                    if (cheb != r) continue;              // shell only
                    int c = (z * G + y) * G + x;
                    int j0 = off[c], j1 = off[c+1];
                    for (int j = j0; j < j1; ++j) {
                        int fi = slist[j];
                        double4 cc4 = ctr4[fi];
                        double dot = qx*cc4.x + qy*cc4.y + qz*cc4.z;
                        double key = cc4.w - 2.0*dot;
                        if (key < bestKey || (key == bestKey && fi < bi)) {
                            bestKey = key; bi = fi;
                        }
                    }
                }
            }
        }
    }
    // exact np d2 for the winning face
    double4 c = ctr4[bi];
    double dot = qx*c.x + qy*c.y + qz*c.z;
    double d2  = (qq - 2.0*dot) + c.w;
    int outlier = (d2 > 0.1) ? 1 : 0;
    fidx_ws[p]  = bi;
    valid_ws[p] = 1 - outlier;
    out[p]        = (float)bi;               // output 0: spt_fidx
    out[3*NP + p] = outlier ? 1.0f : 0.0f;   // output 2: outlier_mask
}

// ---------------------------------------------------------------------------
// K2: denom = max(#valid, 1)
// ---------------------------------------------------------------------------
__global__ __launch_bounds__(256) void k_denom(const int* __restrict__ valid_ws,
                                               double* __restrict__ denom) {
    __shared__ int s[256];
    int acc = 0;
    for (int i = threadIdx.x; i < NP; i += 256) acc += valid_ws[i];
    s[threadIdx.x] = acc;
    __syncthreads();
    for (int off = 128; off > 0; off >>= 1) {
        if (threadIdx.x < off) s[threadIdx.x] += s[threadIdx.x + off];
        __syncthreads();
    }
    if (threadIdx.x == 0) {
        double d = (double)s[0];
        denom[0] = d > 1.0 ? d : 1.0;
    }
}

// ---------------------------------------------------------------------------
// K3: per-point 2x50-step Adagrad — BIT-IDENTICAL to the R4 version
// (measured 47.9µs; per-wave latency floor — occupancy can't shorten an
// in-order wave's own stall chain; numerics frozen at slim vw margin).
// ---------------------------------------------------------------------------
__global__ __launch_bounds__(256) void k_opt(const float* __restrict__ qV,
                                             const float* __restrict__ qN,
                                             const float* __restrict__ mV,
                                             const int* __restrict__ mF,
                                             const float* __restrict__ mN,
                                             const int* __restrict__ fidx_ws,
                                             const int* __restrict__ valid_ws,
                                             const double* __restrict__ denomp,
                                             const double* __restrict__ clrtab,
                                             float* __restrict__ out) {
    int p = blockIdx.x * 256 + threadIdx.x;
    if (p >= NP) return;
    const float third = (float)(1.0/3.0);
    if (!valid_ws[p]) {            // outlier: keeps init barycentric coords
        out[NP + 2*p + 0] = third;
        out[NP + 2*p + 1] = third;
        return;
    }
    double inv_denom = 1.0 / denomp[0];
    int f = fidx_ws[p];
    int i0 = mF[3*f+0], i1 = mF[3*f+1], i2 = mF[3*f+2];

    double V0x = mV[3*i0+0], V0y = mV[3*i0+1], V0z = mV[3*i0+2];
    double V1x = mV[3*i1+0], V1y = mV[3*i1+1], V1z = mV[3*i1+2];
    double V2x = mV[3*i2+0], V2y = mV[3*i2+1], V2z = mV[3*i2+2];
    double N0x = mN[3*i0+0], N0y = mN[3*i0+1], N0z = mN[3*i0+2];
    double N1x = mN[3*i1+0], N1y = mN[3*i1+1], N1z = mN[3*i1+2];
    double N2x = mN[3*i2+0], N2y = mN[3*i2+1], N2z = mN[3*i2+2];
    double qx  = qV[3*p+0],  qy  = qV[3*p+1],  qz  = qV[3*p+2];
    double qnx = qN[3*p+0],  qny = qN[3*p+1],  qnz = qN[3*p+2];

    double Eux = V0x - V2x, Euy = V0y - V2y, Euz = V0z - V2z;  // dcV/du
    double Ewx = V1x - V2x, Ewy = V1y - V2y, Ewz = V1z - V2z;  // dcV/dw
    double Fux = N0x - N2x, Fuy = N0y - N2y, Fuz = N0z - N2z;  // dn_raw/du
    double Fwx = N1x - N2x, Fwy = N1y - N2y, Fwz = N1z - N2z;  // dn_raw/dw
    double Kx  = V2x - qx,  Ky  = V2y - qy,  Kz  = V2z - qz;   // cv - q at uu=ww=0

    double u = 1.0/3.0, w = 1.0/3.0;
    double alpha = 1.0;
    for (int outer = 0; outer < 2; ++outer) {
        double du = 0.0, dw = 0.0, su = 0.0, sw = 0.0;
        for (int it = 0; it < 50; ++it) {
            double uu = u + du, ww = w + dw;
            // position term: rv = cv - q = uu*Eu + ww*Ew + K
            double rvx = uu*Eux + ww*Ewx + Kx;
            double rvy = uu*Euy + ww*Ewy + Ky;
            double rvz = uu*Euz + ww*Ewz + Kz;
            double L2v = rvx*rvx + rvy*rvy + rvz*rvz;
            double invLv = rsqrt(L2v);
            double gu = (rvx*Eux + rvy*Euy + rvz*Euz) * invLv;
            double gw = (rvx*Ewx + rvy*Ewy + rvz*Ewz) * invLv;
            // normal term: n = uu*Fu + ww*Fw + N2
            double nx = uu*Fux + ww*Fwx + N2x;
            double ny = uu*Fuy + ww*Fwy + N2y;
            double nz = uu*Fuz + ww*Fwz + N2z;
            double m2 = nx*nx + ny*ny + nz*nz;
            bool   mok = (m2 > 1e-24);           // <=> m > 1e-12
            double inv = mok ? rsqrt(m2) : 1e12; // 1/max(m,1e-12)
            double hx = nx*inv, hy = ny*inv, hz = nz*inv;
            double rnx = hx - qnx, rny = hy - qny, rnz = hz - qnz;
            double L2n = rnx*rnx + rny*rny + rnz*rnz;
            double invLn = rsqrt(L2n);
            double A_u = rnx*Fux + rny*Fuy + rnz*Fuz;
            double A_w = rnx*Fwx + rny*Fwy + rnz*Fwz;
            double B   = rnx*nx + rny*ny + rnz*nz;
            double C_u = nx*Fux + ny*Fuy + nz*Fuz;
            double C_w = nx*Fwx + ny*Fwy + nz*Fwz;
            // s = B/m^3 when m > eps else 0 (original dropped the term there)
            double s = mok ? ((B*inv)*inv)*inv : 0.0;
            double gnu = (A_u*inv - s*C_u) * invLn;
            double gnw = (A_w*inv - s*C_w) * invLn;
            gu = (gu + 0.01*gnu) * inv_denom;   // mask=1, masked-mean scaling
            gw = (gw + 0.01*gnw) * inv_denom;
            // Adagrad(lr=0.2, lr_decay=0.1)
            su += gu*gu; sw += gw*gw;
            double clr = clrtab[it];
            du -= clr * gu / (sqrt(su) + 1e-10);
            dw -= clr * gw / (sqrt(sw) + 1e-10);
        }
        u += du * alpha; w += dw * alpha;
        alpha *= 0.5;
    }
    out[NP + 2*p + 0] = (float)u;
    out[NP + 2*p + 1] = (float)w;
}

// ---------------------------------------------------------------------------
extern "C" void kernel_launch(void* const* d_in, const int* in_sizes, int n_in,
                              void* d_out, int out_size, void* d_ws, size_t ws_size,
                              hipStream_t stream) {
    const float* qV = (const float*)d_in[0];   // query_V [1,8192,3]
    const float* qN = (const float*)d_in[1];   // query_N [1,8192,3]
    const float* mV = (const float*)d_in[2];   // mesh_V  [16384,3]
    const int*   mF = (const int*)d_in[3];     // mesh_F  [16384,3] int32
    const float* mN = (const float*)d_in[4];   // mesh_N  [16384,3]
    float* out = (float*)d_out;                // fidx | vw | outlier_mask

    double* ctr      = (double*)d_ws;          // NF*4 doubles (512 KB)
    double* denom    = ctr + (size_t)NF*4;     // 1 double
    double* clrtab   = denom + 1;              // 50 doubles
    int*    cellof   = (int*)(clrtab + 50);    // NF ints
    int*    cnt      = cellof + NF;            // NC ints
    int*    off      = cnt + NC;               // NC+1 ints
    int*    cursor   = off + NC + 1;           // NC ints
    int*    slist    = cursor + NC;            // NF ints
    int*    fidx_ws  = slist + NF;             // NP ints
    int*    valid_ws = fidx_ws + NP;           // NP ints

    hipLaunchKernelGGL(k_init,     dim3(NC/256),  dim3(256), 0, stream, cnt, clrtab);
    hipLaunchKernelGGL(k_centers,  dim3(NF/256),  dim3(256), 0, stream, mV, mF, ctr, cellof, cnt);
    hipLaunchKernelGGL(k_prefix,   dim3(1),       dim3(256), 0, stream, cnt, off, cursor);
    hipLaunchKernelGGL(k_scatter,  dim3(NF/256),  dim3(256), 0, stream, cellof, cursor, slist);
    hipLaunchKernelGGL(k_knn_grid, dim3(NP/256),  dim3(256), 0, stream, qV, ctr, off, slist,
                       out, fidx_ws, valid_ws);
    hipLaunchKernelGGL(k_denom,    dim3(1),       dim3(256), 0, stream, valid_ws, denom);
    hipLaunchKernelGGL(k_opt,      dim3(NP/256),  dim3(256), 0, stream,
                       qV, qN, mV, mF, mN, fidx_ws, valid_ws, denom, clrtab, out);
}

// Round 19
// 119.583 us; speedup vs baseline: 6.3128x; 6.3128x over previous
//
#include <hip/hip_runtime.h>
#include <math.h>

#define NP 8192
#define NF 16384
#define G  16                 // grid cells per dim
#define NC (G*G*G)            // 4096 cells
#define H  (1.0/16.0)

// ---------------------------------------------------------------------------
// K_init: zero cell histogram + Adagrad clr table (re-run every call).
// ---------------------------------------------------------------------------
__global__ __launch_bounds__(256) void k_init(int* __restrict__ cnt,
                                              double* __restrict__ clrtab) {
    int t = blockIdx.x * 256 + threadIdx.x;
    if (t < NC) cnt[t] = 0;
    if (blockIdx.x == 0 && threadIdx.x < 50)
        clrtab[threadIdx.x] = 0.2 / (1.0 + (double)threadIdx.x * 0.1);
}

// ---------------------------------------------------------------------------
// K0: face centers in f64 + |c|^2 (np: c=(v0+v1+v2)/3), cell id, histogram.
// ---------------------------------------------------------------------------
__global__ __launch_bounds__(256) void k_centers(const float* __restrict__ mV,
                                                 const int* __restrict__ mF,
                                                 double* __restrict__ ctr,
                                                 int* __restrict__ cellof,
                                                 int* __restrict__ cnt) {
    int f = blockIdx.x * 256 + threadIdx.x;
    if (f >= NF) return;
    int i0 = mF[3*f+0], i1 = mF[3*f+1], i2 = mF[3*f+2];
    double cx = ((double)mV[3*i0+0] + (double)mV[3*i1+0] + (double)mV[3*i2+0]) / 3.0;
    double cy = ((double)mV[3*i0+1] + (double)mV[3*i1+1] + (double)mV[3*i2+1]) / 3.0;
    double cz = ((double)mV[3*i0+2] + (double)mV[3*i1+2] + (double)mV[3*i2+2]) / 3.0;
    ctr[4*f+0] = cx; ctr[4*f+1] = cy; ctr[4*f+2] = cz;
    ctr[4*f+3] = cx*cx + cy*cy + cz*cz;
    int ix = min(G-1, max(0, (int)(cx * (double)G)));
    int iy = min(G-1, max(0, (int)(cy * (double)G)));
    int iz = min(G-1, max(0, (int)(cz * (double)G)));
    int cell = (iz * G + iy) * G + ix;
    cellof[f] = cell;
    atomicAdd(&cnt[cell], 1);
}

// ---------------------------------------------------------------------------
// K_prefix: exclusive prefix sum of the 4096-cell histogram (1 block).
// ---------------------------------------------------------------------------
__global__ __launch_bounds__(256) void k_prefix(const int* __restrict__ cnt,
                                                int* __restrict__ off,
                                                int* __restrict__ cursor) {
    __shared__ int part[256];
    int t = threadIdx.x;
    int base = t * 16;
    int loc[16];
    int s = 0;
    #pragma unroll
    for (int i = 0; i < 16; ++i) { loc[i] = s; s += cnt[base + i]; }
    part[t] = s;
    __syncthreads();
    if (t == 0) {
        int run = 0;
        for (int i = 0; i < 256; ++i) { int v = part[i]; part[i] = run; run += v; }
    }
    __syncthreads();
    int pb = part[t];
    #pragma unroll
    for (int i = 0; i < 16; ++i) {
        off[base + i]    = pb + loc[i];
        cursor[base + i] = pb + loc[i];
    }
    if (t == 255) off[NC] = pb + s;   // == NF
}

// ---------------------------------------------------------------------------
// K_scatter: counting-sort faces into cell-contiguous slist. In-cell order is
// atomic-nondeterministic; downstream lex (key,idx) min is order-independent.
// ---------------------------------------------------------------------------
__global__ __launch_bounds__(256) void k_scatter(const int* __restrict__ cellof,
                                                 int* __restrict__ cursor,
                                                 int* __restrict__ slist) {
    int f = blockIdx.x * 256 + threadIdx.x;
    if (f >= NF) return;
    int c = cellof[f];
    int pos = atomicAdd(&cursor[c], 1);
    slist[pos] = f;
}

// ---------------------------------------------------------------------------
// K1: grid 1-NN, ONE WAVE PER POINT (R18's logic was exact — absmax held —
// but one-THREAD-per-point was latency-serial at 1.2% occupancy, 694µs).
// 64 lanes scan the (2R+1)^3 candidate box in parallel (lane-strided cells,
// ~4 faces each), wave-shfl lex (key,idx) reduce per round. Rounds rescan
// inner cells (box not shell) — lex-min is idempotent, so redundant
// candidates cannot change the winner. Termination (R18-proven): after box
// radius R, unscanned cells are >= R*h away; stop when (R*h)^2 - 1e-9 >
// best + qq (conservative; eps absorbs association ulps) -> winner
// provably == full-scan argmin with first-index tie-break. R=G-1 always
// covers the whole grid (ic in [0,G-1]). Winner's d2 recomputed with np's
// exact association for the outlier test.
// ---------------------------------------------------------------------------
__global__ __launch_bounds__(256) void k_knn_grid(const float* __restrict__ qV,
                                                  const double* __restrict__ ctr,
                                                  const int* __restrict__ off,
                                                  const int* __restrict__ slist,
                                                  float* __restrict__ out,
                                                  int* __restrict__ fidx_ws,
                                                  int* __restrict__ valid_ws) {
    int wid  = threadIdx.x >> 6;
    int lane = threadIdx.x & 63;
    int p = blockIdx.x * 4 + wid;            // 2048 blocks x 4 waves = 8192 pts
    double qx = (double)qV[3*p+0], qy = (double)qV[3*p+1], qz = (double)qV[3*p+2];
    double qq = qx*qx + qy*qy + qz*qz;
    int icx = min(G-1, max(0, (int)(qx * (double)G)));
    int icy = min(G-1, max(0, (int)(qy * (double)G)));
    int icz = min(G-1, max(0, (int)(qz * (double)G)));

    const double4* ctr4 = (const double4*)ctr;
    double best = 1e300; int bidx = 0x7fffffff;   // lane-local, persists
    double gb = 1e300;   int gi = 0x7fffffff;     // wave-global after reduce

    for (int R = 1; R < G; ++R) {
        int W = 2*R + 1;
        int ncell = W*W*W;
        for (int idx = lane; idx < ncell; idx += 64) {
            int lx = idx % W;
            int rem = idx / W;
            int ly = rem % W;
            int lz = rem / W;
            int x = icx + lx - R;
            int y = icy + ly - R;
            int z = icz + lz - R;
            if (x < 0 || x >= G || y < 0 || y >= G || z < 0 || z >= G) continue;
            int c = (z * G + y) * G + x;
            int j0 = off[c], j1 = off[c+1];
            for (int j = j0; j < j1; ++j) {
                int fi = slist[j];
                double4 cc4 = ctr4[fi];
                double dot = qx*cc4.x + qy*cc4.y + qz*cc4.z;
                double key = cc4.w - 2.0*dot;
                if (key < best || (key == best && fi < bidx)) { best = key; bidx = fi; }
            }
        }
        // wave lex-reduce on copies (lane-local partials persist across rounds)
        double tb = best; int ti = bidx;
        #pragma unroll
        for (int o = 32; o > 0; o >>= 1) {
            double ov = __shfl_down(tb, o);
            int    oi = __shfl_down(ti, o);
            if (ov < tb || (ov == tb && oi < ti)) { tb = ov; ti = oi; }
        }
        gb = __shfl(tb, 0);                   // broadcast: uniform branch below
        gi = __shfl(ti, 0);
        double dmin = (double)R * H;
        bool stop = (gi != 0x7fffffff) && (dmin*dmin - 1e-9 > gb + qq);
        if (stop || R == G-1) break;
    }

    if (lane == 0) {
        // exact np d2 for the winning face
        double4 c = ctr4[gi];
        double dot = qx*c.x + qy*c.y + qz*c.z;
        double d2  = (qq - 2.0*dot) + c.w;
        int outlier = (d2 > 0.1) ? 1 : 0;
        fidx_ws[p]  = gi;
        valid_ws[p] = 1 - outlier;
        out[p]        = (float)gi;               // output 0: spt_fidx
        out[3*NP + p] = outlier ? 1.0f : 0.0f;   // output 2: outlier_mask
    }
}

// ---------------------------------------------------------------------------
// K2: denom = max(#valid, 1)
// ---------------------------------------------------------------------------
__global__ __launch_bounds__(256) void k_denom(const int* __restrict__ valid_ws,
                                               double* __restrict__ denom) {
    __shared__ int s[256];
    int acc = 0;
    for (int i = threadIdx.x; i < NP; i += 256) acc += valid_ws[i];
    s[threadIdx.x] = acc;
    __syncthreads();
    for (int off = 128; off > 0; off >>= 1) {
        if (threadIdx.x < off) s[threadIdx.x] += s[threadIdx.x + off];
        __syncthreads();
    }
    if (threadIdx.x == 0) {
        double d = (double)s[0];
        denom[0] = d > 1.0 ? d : 1.0;
    }
}

// ---------------------------------------------------------------------------
// K3: per-point 2x50-step Adagrad — BIT-IDENTICAL to the R4 version
// (measured 47.9µs; per-wave latency floor; numerics frozen at slim margin).
// ---------------------------------------------------------------------------
__global__ __launch_bounds__(256) void k_opt(const float* __restrict__ qV,
                                             const float* __restrict__ qN,
                                             const float* __restrict__ mV,
                                             const int* __restrict__ mF,
                                             const float* __restrict__ mN,
                                             const int* __restrict__ fidx_ws,
                                             const int* __restrict__ valid_ws,
                                             const double* __restrict__ denomp,
                                             const double* __restrict__ clrtab,
                                             float* __restrict__ out) {
    int p = blockIdx.x * 256 + threadIdx.x;
    if (p >= NP) return;
    const float third = (float)(1.0/3.0);
    if (!valid_ws[p]) {            // outlier: keeps init barycentric coords
        out[NP + 2*p + 0] = third;
        out[NP + 2*p + 1] = third;
        return;
    }
    double inv_denom = 1.0 / denomp[0];
    int f = fidx_ws[p];
    int i0 = mF[3*f+0], i1 = mF[3*f+1], i2 = mF[3*f+2];

    double V0x = mV[3*i0+0], V0y = mV[3*i0+1], V0z = mV[3*i0+2];
    double V1x = mV[3*i1+0], V1y = mV[3*i1+1], V1z = mV[3*i1+2];
    double V2x = mV[3*i2+0], V2y = mV[3*i2+1], V2z = mV[3*i2+2];
    double N0x = mN[3*i0+0], N0y = mN[3*i0+1], N0z = mN[3*i0+2];
    double N1x = mN[3*i1+0], N1y = mN[3*i1+1], N1z = mN[3*i1+2];
    double N2x = mN[3*i2+0], N2y = mN[3*i2+1], N2z = mN[3*i2+2];
    double qx  = qV[3*p+0],  qy  = qV[3*p+1],  qz  = qV[3*p+2];
    double qnx = qN[3*p+0],  qny = qN[3*p+1],  qnz = qN[3*p+2];

    double Eux = V0x - V2x, Euy = V0y - V2y, Euz = V0z - V2z;  // dcV/du
    double Ewx = V1x - V2x, Ewy = V1y - V2y, Ewz = V1z - V2z;  // dcV/dw
    double Fux = N0x - N2x, Fuy = N0y - N2y, Fuz = N0z - N2z;  // dn_raw/du
    double Fwx = N1x - N2x, Fwy = N1y - N2y, Fwz = N1z - N2z;  // dn_raw/dw
    double Kx  = V2x - qx,  Ky  = V2y - qy,  Kz  = V2z - qz;   // cv - q at uu=ww=0

    double u = 1.0/3.0, w = 1.0/3.0;
    double alpha = 1.0;
    for (int outer = 0; outer < 2; ++outer) {
        double du = 0.0, dw = 0.0, su = 0.0, sw = 0.0;
        for (int it = 0; it < 50; ++it) {
            double uu = u + du, ww = w + dw;
            // position term: rv = cv - q = uu*Eu + ww*Ew + K
            double rvx = uu*Eux + ww*Ewx + Kx;
            double rvy = uu*Euy + ww*Ewy + Ky;
            double rvz = uu*Euz + ww*Ewz + Kz;
            double L2v = rvx*rvx + rvy*rvy + rvz*rvz;
            double invLv = rsqrt(L2v);
            double gu = (rvx*Eux + rvy*Euy + rvz*Euz) * invLv;
            double gw = (rvx*Ewx + rvy*Ewy + rvz*Ewz) * invLv;
            // normal term: n = uu*Fu + ww*Fw + N2
            double nx = uu*Fux + ww*Fwx + N2x;
            double ny = uu*Fuy + ww*Fwy + N2y;
            double nz = uu*Fuz + ww*Fwz + N2z;
            double m2 = nx*nx + ny*ny + nz*nz;
            bool   mok = (m2 > 1e-24);           // <=> m > 1e-12
            double inv = mok ? rsqrt(m2) : 1e12; // 1/max(m,1e-12)
            double hx = nx*inv, hy = ny*inv, hz = nz*inv;
            double rnx = hx - qnx, rny = hy - qny, rnz = hz - qnz;
            double L2n = rnx*rnx + rny*rny + rnz*rnz;
            double invLn = rsqrt(L2n);
            double A_u = rnx*Fux + rny*Fuy + rnz*Fuz;
            double A_w = rnx*Fwx + rny*Fwy + rnz*Fwz;
            double B   = rnx*nx + rny*ny + rnz*nz;
            double C_u = nx*Fux + ny*Fuy + nz*Fuz;
            double C_w = nx*Fwx + ny*Fwy + nz*Fwz;
            // s = B/m^3 when m > eps else 0 (original dropped the term there)
            double s = mok ? ((B*inv)*inv)*inv : 0.0;
            double gnu = (A_u*inv - s*C_u) * invLn;
            double gnw = (A_w*inv - s*C_w) * invLn;
            gu = (gu + 0.01*gnu) * inv_denom;   // mask=1, masked-mean scaling
            gw = (gw + 0.01*gnw) * inv_denom;
            // Adagrad(lr=0.2, lr_decay=0.1)
            su += gu*gu; sw += gw*gw;
            double clr = clrtab[it];
            du -= clr * gu / (sqrt(su) + 1e-10);
            dw -= clr * gw / (sqrt(sw) + 1e-10);
        }
        u += du * alpha; w += dw * alpha;
        alpha *= 0.5;
    }
    out[NP + 2*p + 0] = (float)u;
    out[NP + 2*p + 1] = (float)w;
}

// ---------------------------------------------------------------------------
extern "C" void kernel_launch(void* const* d_in, const int* in_sizes, int n_in,
                              void* d_out, int out_size, void* d_ws, size_t ws_size,
                              hipStream_t stream) {
    const float* qV = (const float*)d_in[0];   // query_V [1,8192,3]
    const float* qN = (const float*)d_in[1];   // query_N [1,8192,3]
    const float* mV = (const float*)d_in[2];   // mesh_V  [16384,3]
    const int*   mF = (const int*)d_in[3];     // mesh_F  [16384,3] int32
    const float* mN = (const float*)d_in[4];   // mesh_N  [16384,3]
    float* out = (float*)d_out;                // fidx | vw | outlier_mask

    double* ctr      = (double*)d_ws;          // NF*4 doubles (512 KB)
    double* denom    = ctr + (size_t)NF*4;     // 1 double
    double* clrtab   = denom + 1;              // 50 doubles
    int*    cellof   = (int*)(clrtab + 50);    // NF ints
    int*    cnt      = cellof + NF;            // NC ints
    int*    off      = cnt + NC;               // NC+1 ints
    int*    cursor   = off + NC + 1;           // NC ints
    int*    slist    = cursor + NC;            // NF ints
    int*    fidx_ws  = slist + NF;             // NP ints
    int*    valid_ws = fidx_ws + NP;           // NP ints

    hipLaunchKernelGGL(k_init,     dim3(NC/256),  dim3(256), 0, stream, cnt, clrtab);
    hipLaunchKernelGGL(k_centers,  dim3(NF/256),  dim3(256), 0, stream, mV, mF, ctr, cellof, cnt);
    hipLaunchKernelGGL(k_prefix,   dim3(1),       dim3(256), 0, stream, cnt, off, cursor);
    hipLaunchKernelGGL(k_scatter,  dim3(NF/256),  dim3(256), 0, stream, cellof, cursor, slist);
    hipLaunchKernelGGL(k_knn_grid, dim3(NP/4),    dim3(256), 0, stream, qV, ctr, off, slist,
                       out, fidx_ws, valid_ws);
    hipLaunchKernelGGL(k_denom,    dim3(1),       dim3(256), 0, stream, valid_ws, denom);
    hipLaunchKernelGGL(k_opt,      dim3(NP/256),  dim3(256), 0, stream,
                       qV, qN, mV, mF, mN, fidx_ws, valid_ws, denom, clrtab, out);
}